// Round 5
// baseline (675.050 us; speedup 1.0000x reference)
//
#include <hip/hip_runtime.h>
#include <hip/hip_bf16.h>

typedef __hip_bfloat16 bf16;
typedef __attribute__((ext_vector_type(8))) short bf16x8;
typedef __attribute__((ext_vector_type(8))) unsigned short u16x8;
typedef __attribute__((ext_vector_type(4))) float f32x4;

__device__ __forceinline__ float b2f(unsigned short u) {
  return __uint_as_float(((unsigned)u) << 16);
}
__device__ __forceinline__ unsigned short f2b(float x) {
  bf16 h = __float2bfloat16(x);
  return *reinterpret_cast<unsigned short*>(&h);
}

// ---------------- dtype probe (flag=1 -> bf16 storage, 0 -> fp32) ----------------
__global__ void k_probe(const unsigned short* __restrict__ raw, int* __restrict__ flag) {
  __shared__ int sbad, snz;
  const int t = threadIdx.x;
  if (t == 0) { sbad = 0; snz = 0; }
  __syncthreads();
  const unsigned short u = raw[t];
  const float a = fabsf(b2f(u));
  if (!(a < 100.f)) atomicAdd(&sbad, 1);
  if (((t & 1) == 0) && u != 0) atomicAdd(&snz, 1);
  __syncthreads();
  if (t == 0) flag[0] = (sbad == 0 && snz > 0) ? 1 : 0;
}

// ============== deg_out: LDS-privatized histogram (no global atomics) ==============
constexpr int HSLICE = 4096;  // nodes per slice (16 KB LDS)
constexpr int HCHUNK = 8;     // edge chunks

__global__ void k_histA(const int* __restrict__ src, int E, int N, int nslice,
                        int* __restrict__ partial, int Npad) {
  __shared__ int h[HSLICE];
  const int slice = blockIdx.x % nslice;
  const int chunk = blockIdx.x / nslice;
  for (int i = threadIdx.x; i < HSLICE; i += 256) h[i] = 0;
  __syncthreads();
  const int lo = slice * HSLICE;
  const int per = (E + HCHUNK - 1) / HCHUNK;
  const int s = chunk * per;
  const int e = min(E, s + per);
  for (int i = s + threadIdx.x; i < e; i += 256) {
    const unsigned v = (unsigned)(src[i] - lo);
    if (v < (unsigned)HSLICE) atomicAdd(&h[v], 1);
  }
  __syncthreads();
  for (int i = threadIdx.x; i < HSLICE; i += 256) {
    const int node = lo + i;
    if (node < N) partial[chunk * Npad + node] = h[i];
  }
}

__global__ void k_histB(const int* __restrict__ partial, int Npad, int N,
                        int* __restrict__ deg_out) {
  const int node = blockIdx.x * 256 + threadIdx.x;
  if (node < N) {
    int s = 0;
#pragma unroll
    for (int c = 0; c < HCHUNK; ++c) s += partial[c * Npad + node];
    deg_out[node] = s;
  }
}

// ============== LDS counting-sort CSR build (no global atomics) ==============
__global__ void k_passA(const int* __restrict__ dst, int E, int nbuck,
                        int* __restrict__ counts) {
  extern __shared__ int lh[];
  const int t = threadIdx.x;
  for (int k = t; k < nbuck; k += 256) lh[k] = 0;
  __syncthreads();
  const int chunk = (E + 255) / 256;
  const int s = blockIdx.x * chunk;
  const int e = min(E, s + chunk);
  for (int i = s + t; i < e; i += 256) atomicAdd(&lh[dst[i] >> 8], 1);
  __syncthreads();
  for (int k = t; k < nbuck; k += 256) counts[k * 256 + blockIdx.x] = lh[k];
}

__global__ void k_scan1(const int* __restrict__ a, int M, int* __restrict__ bsums) {
  __shared__ int sdata[256];
  int i = blockIdx.x * 256 + threadIdx.x;
  int v = (i < M) ? a[i] : 0;
  sdata[threadIdx.x] = v;
  __syncthreads();
  for (int s = 128; s > 0; s >>= 1) {
    if (threadIdx.x < s) sdata[threadIdx.x] += sdata[threadIdx.x + s];
    __syncthreads();
  }
  if (threadIdx.x == 0) bsums[blockIdx.x] = sdata[0];
}

__global__ void k_scan2(int* __restrict__ bsums, int nb, int* __restrict__ rowStart,
                        int N, int E) {
  __shared__ int s[512];
  const int t = threadIdx.x;
  const int v = (t < nb) ? bsums[t] : 0;
  s[t] = v;
  __syncthreads();
  for (int off = 1; off < 512; off <<= 1) {
    int u = (t >= off) ? s[t - off] : 0;
    __syncthreads();
    s[t] += u;
    __syncthreads();
  }
  if (t < nb) bsums[t] = s[t] - v;  // exclusive
  if (t == 0) rowStart[N] = E;
}

__global__ void k_scan3(int* __restrict__ a, int M, const int* __restrict__ bsums) {
  __shared__ int sdata[256];
  int i = blockIdx.x * 256 + threadIdx.x;
  int v = (i < M) ? a[i] : 0;
  sdata[threadIdx.x] = v;
  __syncthreads();
  for (int off = 1; off < 256; off <<= 1) {
    int t = (threadIdx.x >= off) ? sdata[threadIdx.x - off] : 0;
    __syncthreads();
    sdata[threadIdx.x] += t;
    __syncthreads();
  }
  if (i < M) a[i] = bsums[blockIdx.x] + sdata[threadIdx.x] - v;  // exclusive
}

__global__ void k_passC(const int* __restrict__ src, const int* __restrict__ dst, int E,
                        int nbuck, const int* __restrict__ S, int* __restrict__ tmp) {
  extern __shared__ int cur[];
  const int t = threadIdx.x;
  for (int k = t; k < nbuck; k += 256) cur[k] = S[k * 256 + blockIdx.x];
  __syncthreads();
  const int chunk = (E + 255) / 256;
  const int s = blockIdx.x * chunk;
  const int e = min(E, s + chunk);
  for (int i = s + t; i < e; i += 256) {
    const int d = dst[i];
    const int pos = atomicAdd(&cur[d >> 8], 1);
    tmp[pos] = src[i] | ((d & 255) << 20);
  }
}

__global__ void k_passD(const int* __restrict__ tmp, const int* __restrict__ S,
                        int nbuck, int N, int E, int* __restrict__ deg_in,
                        int* __restrict__ rowStart, int* __restrict__ edgeSrc) {
  __shared__ int h[256];
  __shared__ int ex[256];
  __shared__ int c[256];
  const int t = threadIdx.x;
  const int k = blockIdx.x;
  const int bs = S[k * 256];
  const int be = (k + 1 < nbuck) ? S[(k + 1) * 256] : E;
  h[t] = 0;
  __syncthreads();
  for (int i = bs + t; i < be; i += 256) atomicAdd(&h[tmp[i] >> 20], 1);
  __syncthreads();
  const int node = k * 256 + t;
  const int cnt = h[t];
  if (node < N) deg_in[node] = cnt;
  ex[t] = cnt;
  __syncthreads();
  for (int off = 1; off < 256; off <<= 1) {
    int u = (t >= off) ? ex[t - off] : 0;
    __syncthreads();
    ex[t] += u;
    __syncthreads();
  }
  const int excl = ex[t] - cnt;
  if (node < N) rowStart[node] = bs + excl;
  c[t] = bs + excl;
  __syncthreads();
  for (int i = bs + t; i < be; i += 256) {
    const int v = tmp[i];
    const int pos = atomicAdd(&c[v >> 20], 1);
    edgeSrc[pos] = v & 0xFFFFF;
  }
}

// ---------------- norms ----------------
__global__ void k_norms(const int* __restrict__ deg_out, const int* __restrict__ deg_in, int N,
                        float* __restrict__ ns, float* __restrict__ nd) {
  int i = blockIdx.x * blockDim.x + threadIdx.x;
  if (i < N) {
    int dov = deg_out[i]; if (dov <= 0) dov = 1;
    int div = deg_in[i];  if (div <= 0) div = 1;
    ns[i] = rsqrtf((float)dov);
    nd[i] = rsqrtf((float)div);
  }
}

// ---------------- row-scale proj by norm_src ----------------
__global__ void k_scale(unsigned short* __restrict__ proj, const float* __restrict__ ns, int N) {
  int idx = blockIdx.x * blockDim.x + threadIdx.x;
  if (idx < N * 8) {
    const int node = idx >> 3;
    const float f = ns[node];
    u16x8* p = (u16x8*)(proj + (size_t)node * 64 + (idx & 7) * 8);
    u16x8 v = *p;
#pragma unroll
    for (int j = 0; j < 8; ++j) v[j] = f2b(b2f(v[j]) * f);
    *p = v;
  }
}

// ---------------- MFMA GEMM (pure): out[r][c] = bf16( sum_k h[r][k]*W[k][c] ) ------
template <int K, bool FIRST>
__global__ void k_gemm(const void* __restrict__ hin, const void* __restrict__ Wv,
                       const int* __restrict__ flag, int N,
                       unsigned short* __restrict__ out) {
  const bool isb = (*flag != 0);
  const int lane = threadIdx.x & 63;
  const int quad = lane >> 4;
  const int l16 = lane & 15;
  constexpr int KT = K / 32;

  bf16x8 Bf[KT][4];
  {
    const unsigned short* Wus = (const unsigned short*)Wv;
    const float* Wf = (const float*)Wv;
#pragma unroll
    for (int kt = 0; kt < KT; ++kt)
#pragma unroll
      for (int nt = 0; nt < 4; ++nt)
#pragma unroll
        for (int j = 0; j < 8; ++j) {
          const int k = kt * 32 + quad * 8 + j;
          const int n = nt * 16 + l16;
          const float w = isb ? b2f(Wus[k * 64 + n]) : Wf[k * 64 + n];
          Bf[kt][nt][j] = (short)f2b(w);
        }
  }

  const int wid = (blockIdx.x * blockDim.x + threadIdx.x) >> 6;
  const int nw = (gridDim.x * blockDim.x) >> 6;
  const int G = (N + 15) >> 4;
  for (int g = wid; g < G; g += nw) {
    int rowA = (g << 4) + l16;
    if (rowA >= N) rowA = N - 1;
    f32x4 acc[4] = {{0.f, 0.f, 0.f, 0.f}, {0.f, 0.f, 0.f, 0.f},
                    {0.f, 0.f, 0.f, 0.f}, {0.f, 0.f, 0.f, 0.f}};
#pragma unroll
    for (int kt = 0; kt < KT; ++kt) {
      const int koff = kt * 32 + quad * 8;
      bf16x8 Af;
      if (FIRST && !isb) {
        const float* hp = (const float*)hin + (size_t)rowA * K + koff;
        const float4 u0 = *(const float4*)hp;
        const float4 u1 = *(const float4*)(hp + 4);
        Af[0] = (short)f2b(u0.x); Af[1] = (short)f2b(u0.y);
        Af[2] = (short)f2b(u0.z); Af[3] = (short)f2b(u0.w);
        Af[4] = (short)f2b(u1.x); Af[5] = (short)f2b(u1.y);
        Af[6] = (short)f2b(u1.z); Af[7] = (short)f2b(u1.w);
      } else {
        Af = *(const bf16x8*)((const unsigned short*)hin + (size_t)rowA * K + koff);
      }
      acc[0] = __builtin_amdgcn_mfma_f32_16x16x32_bf16(Af, Bf[kt][0], acc[0], 0, 0, 0);
      acc[1] = __builtin_amdgcn_mfma_f32_16x16x32_bf16(Af, Bf[kt][1], acc[1], 0, 0, 0);
      acc[2] = __builtin_amdgcn_mfma_f32_16x16x32_bf16(Af, Bf[kt][2], acc[2], 0, 0, 0);
      acc[3] = __builtin_amdgcn_mfma_f32_16x16x32_bf16(Af, Bf[kt][3], acc[3], 0, 0, 0);
    }
    const int rowD = (g << 4) + quad * 4;
#pragma unroll
    for (int r = 0; r < 4; ++r) {
      if (rowD + r < N) {
        const size_t o = (size_t)(rowD + r) * 64 + l16;
#pragma unroll
        for (int nt = 0; nt < 4; ++nt)
          out[o + nt * 16] = f2b(acc[nt][r]);
      }
    }
  }
}

// ---------------- aggregation: 2 nodes per wave, interleaved gather chains ----------
// out[n] = relu(nd[n]*sum proj[src] + b) [* ns[n] if !LAST]
template <bool LAST>
__global__ void k_aggregate(const unsigned short* __restrict__ proj,
                            const int* __restrict__ edgeSrc, const int* __restrict__ rowStart,
                            const float* __restrict__ norm_dst, const float* __restrict__ norm_src,
                            const void* __restrict__ bias, const int* __restrict__ flag,
                            int N, void* __restrict__ outp) {
  const bool isb = (*flag != 0);
  const int lane = threadIdx.x & 63;
  const int eo = lane >> 3;
  const int cg = lane & 7;
  float bcol[8];
#pragma unroll
  for (int j = 0; j < 8; ++j)
    bcol[j] = isb ? b2f(((const unsigned short*)bias)[cg * 8 + j])
                  : ((const float*)bias)[cg * 8 + j];
  const int wave = (blockIdx.x * blockDim.x + threadIdx.x) >> 6;
  const int nwaves = (gridDim.x * blockDim.x) >> 6;
  for (int n0 = wave * 2; n0 < N; n0 += nwaves * 2) {
    const int n1 = n0 + 1;
    const int s0 = rowStart[n0];
    const int mid = rowStart[n0 + 1];
    const int e1 = (n1 < N) ? rowStart[n0 + 2] : mid;
    int base0 = s0, cnt0 = mid - s0;
    int base1 = mid, cnt1 = e1 - mid;
    float a0[8] = {0.f, 0.f, 0.f, 0.f, 0.f, 0.f, 0.f, 0.f};
    float a1[8] = {0.f, 0.f, 0.f, 0.f, 0.f, 0.f, 0.f, 0.f};
    while (cnt0 > 0 || cnt1 > 0) {
      const int take0 = cnt0 < 64 ? cnt0 : 64;
      const int take1 = cnt1 < 64 ? cnt1 : 64;
      const int idx0 = (lane < take0) ? edgeSrc[base0 + lane] : 0;
      const int idx1 = (lane < take1) ? edgeSrc[base1 + lane] : 0;
      const int tmax = take0 > take1 ? take0 : take1;
      for (int c = 0; c < tmax; c += 8) {
        const int sl = c + eo;
        if (c < take0) {
          const int sn = __shfl(idx0, sl, 64);
          if (sl < take0) {
            const u16x8 v = *(const u16x8*)(proj + (size_t)sn * 64 + cg * 8);
#pragma unroll
            for (int j = 0; j < 8; ++j) a0[j] += b2f(v[j]);
          }
        }
        if (c < take1) {
          const int sn = __shfl(idx1, sl, 64);
          if (sl < take1) {
            const u16x8 v = *(const u16x8*)(proj + (size_t)sn * 64 + cg * 8);
#pragma unroll
            for (int j = 0; j < 8; ++j) a1[j] += b2f(v[j]);
          }
        }
      }
      base0 += take0; cnt0 -= take0;
      base1 += take1; cnt1 -= take1;
    }
#pragma unroll
    for (int j = 0; j < 8; ++j) {
      a0[j] += __shfl_xor(a0[j], 8, 64);
      a0[j] += __shfl_xor(a0[j], 16, 64);
      a0[j] += __shfl_xor(a0[j], 32, 64);
      a1[j] += __shfl_xor(a1[j], 8, 64);
      a1[j] += __shfl_xor(a1[j], 16, 64);
      a1[j] += __shfl_xor(a1[j], 32, 64);
    }
    if (eo < 2) {
      const int n = (eo == 0) ? n0 : n1;
      if (n < N) {
        const float nd = norm_dst[n];
        float r[8];
#pragma unroll
        for (int j = 0; j < 8; ++j) {
          const float av = (eo == 0) ? a0[j] : a1[j];
          r[j] = fmaxf(fmaf(av, nd, bcol[j]), 0.f);
        }
        if (!LAST) {
          const float esc = norm_src[n];
#pragma unroll
          for (int j = 0; j < 8; ++j) r[j] *= esc;
        }
        if (LAST && !isb) {
          float* of = (float*)outp + (size_t)n * 64 + cg * 8;
          float4 o0; o0.x = r[0]; o0.y = r[1]; o0.z = r[2]; o0.w = r[3];
          float4 o1; o1.x = r[4]; o1.y = r[5]; o1.z = r[6]; o1.w = r[7];
          *(float4*)of = o0;
          *(float4*)(of + 4) = o1;
        } else {
          u16x8 o;
#pragma unroll
          for (int j = 0; j < 8; ++j) o[j] = f2b(r[j]);
          *(u16x8*)((unsigned short*)outp + (size_t)n * 64 + cg * 8) = o;
        }
      }
    }
  }
}

extern "C" void kernel_launch(void* const* d_in, const int* in_sizes, int n_in,
                              void* d_out, int out_size, void* d_ws, size_t ws_size,
                              hipStream_t stream) {
  const void* features = d_in[0];
  const void* W0 = d_in[1];
  const void* b0 = d_in[2];
  const void* W1 = d_in[3];
  const void* b1 = d_in[4];
  const void* W2 = d_in[5];
  const void* b2 = d_in[6];
  const int* src = (const int*)d_in[7];
  const int* dst = (const int*)d_in[8];
  const int N = in_sizes[0] / 128;
  const int E = in_sizes[7];
  const int NBUCK = (N + 255) >> 8;
  const int M = NBUCK * 256;
  const int NSLICE = (N + HSLICE - 1) / HSLICE;
  const int Npad = NSLICE * HSLICE;

  char* w = (char*)d_ws;
  size_t off = 0;
  auto alloc = [&](size_t bytes) {
    void* p = w + off;
    off = (off + bytes + 255) & ~(size_t)255;
    return p;
  };
  int* deg_out = (int*)alloc((size_t)N * 4);
  int* deg_in = (int*)alloc((size_t)N * 4);
  int* flag = (int*)alloc(4);
  int* rowStart = (int*)alloc((size_t)(N + 1) * 4);
  int* counts = (int*)alloc((size_t)M * 4);
  int* bsums = (int*)alloc(512 * 4);
  float* norm_src = (float*)alloc((size_t)N * 4);
  float* norm_dst = (float*)alloc((size_t)N * 4);
  int* tmp = (int*)alloc((size_t)E * 4);
  int* edgeSrc = (int*)alloc((size_t)E * 4);
  int* partial = (int*)alloc((size_t)HCHUNK * Npad * 4);
  unsigned short* projA = (unsigned short*)alloc((size_t)N * 64 * 2);  // bf16
  unsigned short* hB = (unsigned short*)d_out;  // inter-layer h (bf16) in d_out

  k_probe<<<1, 256, 0, stream>>>((const unsigned short*)features, flag);

  const int GB = ((N + 15) / 16 + 3) / 4;
  // gemm0 (pure; norm folded in later by k_scale)
  k_gemm<128, true><<<GB, 256, 0, stream>>>(features, W0, flag, N, projA);

  // deg_out: LDS-privatized histogram
  k_histA<<<NSLICE * HCHUNK, 256, 0, stream>>>(src, E, N, NSLICE, partial, Npad);
  k_histB<<<(N + 255) / 256, 256, 0, stream>>>(partial, Npad, N, deg_out);

  // CSR build: LDS counting sort
  const size_t lds_nb = (size_t)NBUCK * 4;
  k_passA<<<256, 256, lds_nb, stream>>>(dst, E, NBUCK, counts);
  const int NB2 = (M + 255) / 256;  // == NBUCK
  k_scan1<<<NB2, 256, 0, stream>>>(counts, M, bsums);
  k_scan2<<<1, 512, 0, stream>>>(bsums, NB2, rowStart, N, E);
  k_scan3<<<NB2, 256, 0, stream>>>(counts, M, bsums);
  k_passC<<<256, 256, lds_nb, stream>>>(src, dst, E, NBUCK, counts, tmp);
  k_passD<<<NBUCK, 256, 0, stream>>>(tmp, counts, NBUCK, N, E, deg_in, rowStart, edgeSrc);

  k_norms<<<(N + 255) / 256, 256, 0, stream>>>(deg_out, deg_in, N, norm_src, norm_dst);
  k_scale<<<(N * 8 + 255) / 256, 256, 0, stream>>>(projA, norm_src, N);

  const int AB = ((N + 1) / 2 + 3) / 4;  // 2 nodes per wave, 4 waves/block
  // layer 0
  k_aggregate<false><<<AB, 256, 0, stream>>>(projA, edgeSrc, rowStart, norm_dst, norm_src, b0, flag, N, hB);
  // layer 1 (h pre-scaled by ns in agg epilogue)
  k_gemm<64, false><<<GB, 256, 0, stream>>>(hB, W1, flag, N, projA);
  k_aggregate<false><<<AB, 256, 0, stream>>>(projA, edgeSrc, rowStart, norm_dst, norm_src, b1, flag, N, hB);
  // layer 2 -> d_out
  k_gemm<64, false><<<GB, 256, 0, stream>>>(hB, W2, flag, N, projA);
  k_aggregate<true><<<AB, 256, 0, stream>>>(projA, edgeSrc, rowStart, norm_dst, norm_src, b2, flag, N, d_out);
}

// Round 6
// 413.379 us; speedup vs baseline: 1.6330x; 1.6330x over previous
//
#include <hip/hip_runtime.h>
#include <hip/hip_bf16.h>

typedef __hip_bfloat16 bf16;
typedef __attribute__((ext_vector_type(8))) short bf16x8;
typedef __attribute__((ext_vector_type(8))) unsigned short u16x8;
typedef __attribute__((ext_vector_type(4))) float f32x4;

__device__ __forceinline__ float b2f(unsigned short u) {
  return __uint_as_float(((unsigned)u) << 16);
}
__device__ __forceinline__ unsigned short f2b(float x) {
  bf16 h = __float2bfloat16(x);
  return *reinterpret_cast<unsigned short*>(&h);
}

// ---------------- dtype probe (flag=1 -> bf16 storage, 0 -> fp32) ----------------
__global__ void k_probe(const unsigned short* __restrict__ raw, int* __restrict__ flag) {
  __shared__ int sbad, snz;
  const int t = threadIdx.x;
  if (t == 0) { sbad = 0; snz = 0; }
  __syncthreads();
  const unsigned short u = raw[t];
  const float a = fabsf(b2f(u));
  if (!(a < 100.f)) atomicAdd(&sbad, 1);
  if (((t & 1) == 0) && u != 0) atomicAdd(&snz, 1);
  __syncthreads();
  if (t == 0) flag[0] = (sbad == 0 && snz > 0) ? 1 : 0;
}

// ============== LDS counting-sort CSR build ==============
// passA: per-(coarse bucket, chunk-block) counts of dst>>8. 256 blocks.
__global__ void k_passA(const int* __restrict__ dst, int E, int nbuck,
                        int* __restrict__ counts) {
  extern __shared__ int lh[];
  const int t = threadIdx.x;
  for (int k = t; k < nbuck; k += 256) lh[k] = 0;
  __syncthreads();
  const int chunk = (E + 255) / 256;
  const int s = blockIdx.x * chunk;
  const int e = min(E, s + chunk);
  for (int i = s + t; i < e; i += 256) atomicAdd(&lh[dst[i] >> 8], 1);
  __syncthreads();
  for (int k = t; k < nbuck; k += 256) counts[k * 256 + blockIdx.x] = lh[k];
}

__global__ void k_scan1(const int* __restrict__ a, int M, int* __restrict__ bsums) {
  __shared__ int sdata[256];
  int i = blockIdx.x * 256 + threadIdx.x;
  int v = (i < M) ? a[i] : 0;
  sdata[threadIdx.x] = v;
  __syncthreads();
  for (int s = 128; s > 0; s >>= 1) {
    if (threadIdx.x < s) sdata[threadIdx.x] += sdata[threadIdx.x + s];
    __syncthreads();
  }
  if (threadIdx.x == 0) bsums[blockIdx.x] = sdata[0];
}

__global__ void k_scan2(int* __restrict__ bsums, int nb, int* __restrict__ rowStart,
                        int N, int E) {
  __shared__ int s[512];
  const int t = threadIdx.x;
  const int v = (t < nb) ? bsums[t] : 0;
  s[t] = v;
  __syncthreads();
  for (int off = 1; off < 512; off <<= 1) {
    int u = (t >= off) ? s[t - off] : 0;
    __syncthreads();
    s[t] += u;
    __syncthreads();
  }
  if (t < nb) bsums[t] = s[t] - v;  // exclusive
  if (t == 0) rowStart[N] = E;
}

__global__ void k_scan3(int* __restrict__ a, int M, const int* __restrict__ bsums) {
  __shared__ int sdata[256];
  int i = blockIdx.x * 256 + threadIdx.x;
  int v = (i < M) ? a[i] : 0;
  sdata[threadIdx.x] = v;
  __syncthreads();
  for (int off = 1; off < 256; off <<= 1) {
    int t = (threadIdx.x >= off) ? sdata[threadIdx.x - off] : 0;
    __syncthreads();
    sdata[threadIdx.x] += t;
    __syncthreads();
  }
  if (i < M) a[i] = bsums[blockIdx.x] + sdata[threadIdx.x] - v;  // exclusive
}

// passC: scatter packed (src | (dst&255)<<20) into bucket-grouped tmp.
// FUSED: deg_out global-atomic histogram (reuses the src load; the fire-and-
// forget atomic drain overlaps the scatter work instead of costing a kernel).
__global__ void k_passC(const int* __restrict__ src, const int* __restrict__ dst, int E,
                        int nbuck, const int* __restrict__ S, int* __restrict__ tmp,
                        int* __restrict__ deg_out) {
  extern __shared__ int cur[];
  const int t = threadIdx.x;
  for (int k = t; k < nbuck; k += 256) cur[k] = S[k * 256 + blockIdx.x];
  __syncthreads();
  const int chunk = (E + 255) / 256;
  const int s = blockIdx.x * chunk;
  const int e = min(E, s + chunk);
  for (int i = s + t; i < e; i += 256) {
    const int sv = src[i];
    const int d = dst[i];
    atomicAdd(&deg_out[sv], 1);
    const int pos = atomicAdd(&cur[d >> 8], 1);
    tmp[pos] = sv | ((d & 255) << 20);
  }
}

// passD: per-bucket: deg_in hist + LDS scan -> rowStart, norms, edgeSrc scatter.
__global__ void k_passD(const int* __restrict__ tmp, const int* __restrict__ S,
                        int nbuck, int N, int E, const int* __restrict__ deg_out,
                        int* __restrict__ rowStart, int* __restrict__ edgeSrc,
                        float* __restrict__ ns, float* __restrict__ nd) {
  __shared__ int h[256];
  __shared__ int ex[256];
  __shared__ int c[256];
  const int t = threadIdx.x;
  const int k = blockIdx.x;
  const int bs = S[k * 256];
  const int be = (k + 1 < nbuck) ? S[(k + 1) * 256] : E;
  h[t] = 0;
  __syncthreads();
  for (int i = bs + t; i < be; i += 256) atomicAdd(&h[tmp[i] >> 20], 1);
  __syncthreads();
  const int node = k * 256 + t;
  const int cnt = h[t];
  ex[t] = cnt;
  __syncthreads();
  for (int off = 1; off < 256; off <<= 1) {
    int u = (t >= off) ? ex[t - off] : 0;
    __syncthreads();
    ex[t] += u;
    __syncthreads();
  }
  const int excl = ex[t] - cnt;
  if (node < N) {
    rowStart[node] = bs + excl;
    const int div = (cnt > 0) ? cnt : 1;
    nd[node] = rsqrtf((float)div);
    int dov = deg_out[node];
    if (dov <= 0) dov = 1;
    ns[node] = rsqrtf((float)dov);
  }
  c[t] = bs + excl;
  __syncthreads();
  for (int i = bs + t; i < be; i += 256) {
    const int v = tmp[i];
    const int pos = atomicAdd(&c[v >> 20], 1);
    edgeSrc[pos] = v & 0xFFFFF;
  }
}

// ---------------- MFMA GEMM: out[r][c] = bf16( [ns[r]*] sum_k h[r][k]*W[k][c] ) ------
// 16x16x32 bf16; A[m=lane&15][k=quad*8+j]; B[k][n=lane&15]; D col=lane&15,row=quad*4+reg
template <int K, bool FIRST, bool SCALE>
__global__ void k_gemm(const void* __restrict__ hin, const void* __restrict__ Wv,
                       const int* __restrict__ flag, const float* __restrict__ norm_src,
                       int N, unsigned short* __restrict__ out) {
  const bool isb = (*flag != 0);
  const int lane = threadIdx.x & 63;
  const int quad = lane >> 4;
  const int l16 = lane & 15;
  constexpr int KT = K / 32;

  bf16x8 Bf[KT][4];
  {
    const unsigned short* Wus = (const unsigned short*)Wv;
    const float* Wf = (const float*)Wv;
#pragma unroll
    for (int kt = 0; kt < KT; ++kt)
#pragma unroll
      for (int nt = 0; nt < 4; ++nt)
#pragma unroll
        for (int j = 0; j < 8; ++j) {
          const int k = kt * 32 + quad * 8 + j;
          const int n = nt * 16 + l16;
          const float w = isb ? b2f(Wus[k * 64 + n]) : Wf[k * 64 + n];
          Bf[kt][nt][j] = (short)f2b(w);
        }
  }

  const int wid = (blockIdx.x * blockDim.x + threadIdx.x) >> 6;
  const int nw = (gridDim.x * blockDim.x) >> 6;
  const int G = (N + 15) >> 4;
  for (int g = wid; g < G; g += nw) {
    int rowA = (g << 4) + l16;
    if (rowA >= N) rowA = N - 1;
    f32x4 acc[4] = {{0.f, 0.f, 0.f, 0.f}, {0.f, 0.f, 0.f, 0.f},
                    {0.f, 0.f, 0.f, 0.f}, {0.f, 0.f, 0.f, 0.f}};
#pragma unroll
    for (int kt = 0; kt < KT; ++kt) {
      const int koff = kt * 32 + quad * 8;
      bf16x8 Af;
      if (FIRST && !isb) {
        const float* hp = (const float*)hin + (size_t)rowA * K + koff;
        const float4 u0 = *(const float4*)hp;
        const float4 u1 = *(const float4*)(hp + 4);
        Af[0] = (short)f2b(u0.x); Af[1] = (short)f2b(u0.y);
        Af[2] = (short)f2b(u0.z); Af[3] = (short)f2b(u0.w);
        Af[4] = (short)f2b(u1.x); Af[5] = (short)f2b(u1.y);
        Af[6] = (short)f2b(u1.z); Af[7] = (short)f2b(u1.w);
      } else {
        Af = *(const bf16x8*)((const unsigned short*)hin + (size_t)rowA * K + koff);
      }
      acc[0] = __builtin_amdgcn_mfma_f32_16x16x32_bf16(Af, Bf[kt][0], acc[0], 0, 0, 0);
      acc[1] = __builtin_amdgcn_mfma_f32_16x16x32_bf16(Af, Bf[kt][1], acc[1], 0, 0, 0);
      acc[2] = __builtin_amdgcn_mfma_f32_16x16x32_bf16(Af, Bf[kt][2], acc[2], 0, 0, 0);
      acc[3] = __builtin_amdgcn_mfma_f32_16x16x32_bf16(Af, Bf[kt][3], acc[3], 0, 0, 0);
    }
    const int rowD = (g << 4) + quad * 4;
#pragma unroll
    for (int r = 0; r < 4; ++r) {
      if (rowD + r < N) {
        const float f = SCALE ? norm_src[rowD + r] : 1.0f;
        const size_t o = (size_t)(rowD + r) * 64 + l16;
#pragma unroll
        for (int nt = 0; nt < 4; ++nt)
          out[o + nt * 16] = f2b(SCALE ? acc[nt][r] * f : acc[nt][r]);
      }
    }
  }
}

// ---------------- aggregation: 2 nodes per wave, interleaved gather chains ----------
// out[n] = relu(nd[n]*sum proj[src] + b) [* ns[n] if !LAST]
template <bool LAST>
__global__ void k_aggregate(const unsigned short* __restrict__ proj,
                            const int* __restrict__ edgeSrc, const int* __restrict__ rowStart,
                            const float* __restrict__ norm_dst, const float* __restrict__ norm_src,
                            const void* __restrict__ bias, const int* __restrict__ flag,
                            int N, void* __restrict__ outp) {
  const bool isb = (*flag != 0);
  const int lane = threadIdx.x & 63;
  const int eo = lane >> 3;
  const int cg = lane & 7;
  float bcol[8];
#pragma unroll
  for (int j = 0; j < 8; ++j)
    bcol[j] = isb ? b2f(((const unsigned short*)bias)[cg * 8 + j])
                  : ((const float*)bias)[cg * 8 + j];
  const int wave = (blockIdx.x * blockDim.x + threadIdx.x) >> 6;
  const int nwaves = (gridDim.x * blockDim.x) >> 6;
  for (int n0 = wave * 2; n0 < N; n0 += nwaves * 2) {
    const int n1 = n0 + 1;
    const int s0 = rowStart[n0];
    const int mid = rowStart[n0 + 1];
    const int e1 = (n1 < N) ? rowStart[n0 + 2] : mid;
    int base0 = s0, cnt0 = mid - s0;
    int base1 = mid, cnt1 = e1 - mid;
    float a0[8] = {0.f, 0.f, 0.f, 0.f, 0.f, 0.f, 0.f, 0.f};
    float a1[8] = {0.f, 0.f, 0.f, 0.f, 0.f, 0.f, 0.f, 0.f};
    while (cnt0 > 0 || cnt1 > 0) {
      const int take0 = cnt0 < 64 ? cnt0 : 64;
      const int take1 = cnt1 < 64 ? cnt1 : 64;
      const int idx0 = (lane < take0) ? edgeSrc[base0 + lane] : 0;
      const int idx1 = (lane < take1) ? edgeSrc[base1 + lane] : 0;
      const int tmax = take0 > take1 ? take0 : take1;
      for (int c = 0; c < tmax; c += 8) {
        const int sl = c + eo;
        if (c < take0) {
          const int sn = __shfl(idx0, sl, 64);
          if (sl < take0) {
            const u16x8 v = *(const u16x8*)(proj + (size_t)sn * 64 + cg * 8);
#pragma unroll
            for (int j = 0; j < 8; ++j) a0[j] += b2f(v[j]);
          }
        }
        if (c < take1) {
          const int sn = __shfl(idx1, sl, 64);
          if (sl < take1) {
            const u16x8 v = *(const u16x8*)(proj + (size_t)sn * 64 + cg * 8);
#pragma unroll
            for (int j = 0; j < 8; ++j) a1[j] += b2f(v[j]);
          }
        }
      }
      base0 += take0; cnt0 -= take0;
      base1 += take1; cnt1 -= take1;
    }
#pragma unroll
    for (int j = 0; j < 8; ++j) {
      a0[j] += __shfl_xor(a0[j], 8, 64);
      a0[j] += __shfl_xor(a0[j], 16, 64);
      a0[j] += __shfl_xor(a0[j], 32, 64);
      a1[j] += __shfl_xor(a1[j], 8, 64);
      a1[j] += __shfl_xor(a1[j], 16, 64);
      a1[j] += __shfl_xor(a1[j], 32, 64);
    }
    if (eo < 2) {
      const int n = (eo == 0) ? n0 : n1;
      if (n < N) {
        const float nd = norm_dst[n];
        float r[8];
#pragma unroll
        for (int j = 0; j < 8; ++j) {
          const float av = (eo == 0) ? a0[j] : a1[j];
          r[j] = fmaxf(fmaf(av, nd, bcol[j]), 0.f);
        }
        if (!LAST) {
          const float esc = norm_src[n];
#pragma unroll
          for (int j = 0; j < 8; ++j) r[j] *= esc;
        }
        if (LAST && !isb) {
          float* of = (float*)outp + (size_t)n * 64 + cg * 8;
          float4 o0; o0.x = r[0]; o0.y = r[1]; o0.z = r[2]; o0.w = r[3];
          float4 o1; o1.x = r[4]; o1.y = r[5]; o1.z = r[6]; o1.w = r[7];
          *(float4*)of = o0;
          *(float4*)(of + 4) = o1;
        } else {
          u16x8 o;
#pragma unroll
          for (int j = 0; j < 8; ++j) o[j] = f2b(r[j]);
          *(u16x8*)((unsigned short*)outp + (size_t)n * 64 + cg * 8) = o;
        }
      }
    }
  }
}

extern "C" void kernel_launch(void* const* d_in, const int* in_sizes, int n_in,
                              void* d_out, int out_size, void* d_ws, size_t ws_size,
                              hipStream_t stream) {
  const void* features = d_in[0];
  const void* W0 = d_in[1];
  const void* b0 = d_in[2];
  const void* W1 = d_in[3];
  const void* b1 = d_in[4];
  const void* W2 = d_in[5];
  const void* b2 = d_in[6];
  const int* src = (const int*)d_in[7];
  const int* dst = (const int*)d_in[8];
  const int N = in_sizes[0] / 128;
  const int E = in_sizes[7];
  const int NBUCK = (N + 255) >> 8;
  const int M = NBUCK * 256;

  char* w = (char*)d_ws;
  size_t off = 0;
  auto alloc = [&](size_t bytes) {
    void* p = w + off;
    off = (off + bytes + 255) & ~(size_t)255;
    return p;
  };
  int* deg_out = (int*)alloc((size_t)N * 4);
  const size_t zero_bytes = off;  // only deg_out needs zeroing
  int* flag = (int*)alloc(4);
  int* rowStart = (int*)alloc((size_t)(N + 1) * 4);
  int* counts = (int*)alloc((size_t)M * 4);
  int* bsums = (int*)alloc(512 * 4);
  float* norm_src = (float*)alloc((size_t)N * 4);
  float* norm_dst = (float*)alloc((size_t)N * 4);
  int* tmp = (int*)alloc((size_t)E * 4);
  int* edgeSrc = (int*)alloc((size_t)E * 4);
  unsigned short* projA = (unsigned short*)alloc((size_t)N * 64 * 2);  // bf16
  unsigned short* hB = (unsigned short*)d_out;  // inter-layer h (bf16) in d_out

  hipMemsetAsync(d_ws, 0, zero_bytes, stream);
  k_probe<<<1, 256, 0, stream>>>((const unsigned short*)features, flag);

  // CSR build (LDS counting sort); passC also drains the deg_out atomic hist.
  const size_t lds_nb = (size_t)NBUCK * 4;
  k_passA<<<256, 256, lds_nb, stream>>>(dst, E, NBUCK, counts);
  const int NB2 = (M + 255) / 256;  // == NBUCK
  k_scan1<<<NB2, 256, 0, stream>>>(counts, M, bsums);
  k_scan2<<<1, 512, 0, stream>>>(bsums, NB2, rowStart, N, E);
  k_scan3<<<NB2, 256, 0, stream>>>(counts, M, bsums);
  k_passC<<<256, 256, lds_nb, stream>>>(src, dst, E, NBUCK, counts, tmp, deg_out);
  k_passD<<<NBUCK, 256, 0, stream>>>(tmp, counts, NBUCK, N, E, deg_out,
                                     rowStart, edgeSrc, norm_src, norm_dst);

  const int GB = ((N + 15) / 16 + 3) / 4;
  const int AB = ((N + 1) / 2 + 3) / 4;  // 2 nodes/wave, 4 waves/block
  // layer 0 (ns folded into gemm0 epilogue)
  k_gemm<128, true, true><<<GB, 256, 0, stream>>>(features, W0, flag, norm_src, N, projA);
  k_aggregate<false><<<AB, 256, 0, stream>>>(projA, edgeSrc, rowStart, norm_dst, norm_src, b0, flag, N, hB);
  // layer 1 (h pre-scaled by ns in agg epilogue)
  k_gemm<64, false, false><<<GB, 256, 0, stream>>>(hB, W1, flag, nullptr, N, projA);
  k_aggregate<false><<<AB, 256, 0, stream>>>(projA, edgeSrc, rowStart, norm_dst, norm_src, b1, flag, N, hB);
  // layer 2 -> d_out
  k_gemm<64, false, false><<<GB, 256, 0, stream>>>(hB, W2, flag, nullptr, N, projA);
  k_aggregate<true><<<AB, 256, 0, stream>>>(projA, edgeSrc, rowStart, norm_dst, norm_src, b2, flag, N, d_out);
}